// Round 4
// baseline (156.644 us; speedup 1.0000x reference)
//
#include <hip/hip_runtime.h>
#include <hip/hip_bf16.h>

// Problem constants
#define FMAPS 128     // feature maps
#define SEQL  512     // L
#define BATCH 64      // B
#define EMB   300     // embedding dim
#define EMBP  320     // padded embedding dim -> K = 3*320 = 960 = 30 * 32
#define LPAD  514     // L + 2 (conv padding rows)
#define NKC   30      // K-chunks of 32
#define NROI  2048
#define FFDIM 512     // FEATURE_MAPS * POOLING_OUT
#define NCLS  8       // CLASSES + 1

// fused prep kernel grid carve-up (all blocks 256 threads)
#define PAD_BLOCKS  10280   // 64*514*80 quads / 256
#define WPAD_BLOCKS 480     // 30*8*64*8 / 256
#define MF_BLOCKS   8       // one per class
#define B2_BLOCKS   1

typedef short bf16x8 __attribute__((ext_vector_type(8)));   // 8 bf16 (4 VGPRs)
typedef float f32x4  __attribute__((ext_vector_type(4)));   // MFMA accumulator

static __device__ __forceinline__ float relu_(float x) { return x > 0.f ? x : 0.f; }
static __device__ __forceinline__ ushort bf16bits(float f) {
    __hip_bfloat16 h = __float2bfloat16(f);
    return *reinterpret_cast<ushort*>(&h);
}

// ---------------------------------------------------------------------------
// 1. Fused prep (heterogeneous grid):
//    [0, PAD)        : pad sentence fp32 [B,512,300] -> Xp bf16 [B,514,320]
//    [PAD, +WPAD)    : conv_w -> WF fragment-major bf16
//                      WF[kc][nt][lane][j] = W[kc*32+(lane>>4)*8+j][nt*16+(lane&15)]
//    [.., +8)        : Mf[c][g] = sum_i cls_w[c][i] * sum_p fc1_w[i][4g+p]
//    last block      : b2[c] = cls_b[c] + cls_w[c]·fc1_b
// ---------------------------------------------------------------------------
__global__ __launch_bounds__(256) void prep_fused(
    const float* __restrict__ x, const float* __restrict__ conv_w,
    const float* __restrict__ cls_w, const float* __restrict__ fc1_w,
    const float* __restrict__ fc1_b, const float* __restrict__ cls_b,
    ushort* __restrict__ xp, ushort* __restrict__ wf,
    float* __restrict__ Mf, float* __restrict__ b2) {
    __shared__ float red[2][128];
    const int tid = threadIdx.x;
    int blk = blockIdx.x;

    if (blk < PAD_BLOCKS) {
        const int ROW4 = EMBP / 4;                 // 80 quads per padded row
        int idx = blk * 256 + tid;                 // < 2,631,680 exactly
        int d4 = idx % ROW4;
        int t  = idx / ROW4;
        int r  = t % LPAD;
        int b  = t / LPAD;
        float4 v = make_float4(0.f, 0.f, 0.f, 0.f);
        if (r >= 1 && r <= SEQL && d4 < (EMB / 4)) {
            v = ((const float4*)(x + ((size_t)(b * SEQL + (r - 1))) * EMB))[d4];
        }
        ushort4 o;
        o.x = bf16bits(v.x); o.y = bf16bits(v.y); o.z = bf16bits(v.z); o.w = bf16bits(v.w);
        ((ushort4*)xp)[idx] = o;
        return;
    }
    blk -= PAD_BLOCKS;

    if (blk < WPAD_BLOCKS) {
        int idx = blk * 256 + tid;                 // < 122,880 exactly
        int j    = idx & 7;
        int lane = (idx >> 3) & 63;
        int nt   = (idx >> 9) & 7;
        int kc   = idx >> 12;
        int f = nt * 16 + (lane & 15);
        int k = kc * 32 + (lane >> 4) * 8 + j;
        int kr = k / EMBP, d = k % EMBP;
        float v = (d < EMB) ? conv_w[f * 900 + kr * 300 + d] : 0.f;
        wf[idx] = bf16bits(v);
        return;
    }
    blk -= WPAD_BLOCKS;

    if (blk < MF_BLOCKS) {
        const int c = blk;
        const int g = tid & 127;
        const int q = tid >> 7;                    // i-half
        float s = 0.f;
        for (int i = q * 256; i < q * 256 + 256; ++i) {
            float4 w4 = *(const float4*)(fc1_w + (size_t)i * FFDIM + 4 * g);
            float ws = (w4.x + w4.y) + (w4.z + w4.w);
            s = fmaf(cls_w[c * FFDIM + i], ws, s);
        }
        red[q][g] = s;
        __syncthreads();
        if (tid < 128) Mf[c * FMAPS + tid] = red[0][tid] + red[1][tid];
        return;
    }

    // b2 block: 8 classes x 32-lane groups
    {
        const int c = tid >> 5;
        const int l32 = tid & 31;
        float s = 0.f;
        for (int i = l32; i < FFDIM; i += 32)
            s = fmaf(cls_w[c * FFDIM + i], fc1_b[i], s);
#pragma unroll
        for (int off = 16; off; off >>= 1) s += __shfl_xor(s, off, 64);
        if (l32 == 0) b2[c] = s + cls_b[c];
    }
}

// ---------------------------------------------------------------------------
// 2. Conv as LDS-free MFMA GEMM, v2 (occupancy-doubled).
//    C[M=32768][N=128] = A[M][K=960] * B[K][128], bf16 in, fp32 out + bias + relu.
//    Block: 512 thr = 8 waves (2 wm x 4 wn); wave tile 32x32 (M_rep=2, N_rep=2).
//    4096 waves total = 4 waves/SIMD. Operand traffic unchanged vs v1.
//    A-frag: lane holds Xp[b][row + kr][dc*32 + (lane>>4)*8 + 0..7]
//    B-frag: WF fragment-major, 1KB per wave-load, L2-hot.
// ---------------------------------------------------------------------------
__global__ __launch_bounds__(512, 4) void conv_mfma(
    const ushort* __restrict__ xp, const ushort* __restrict__ wf,
    const float* __restrict__ cb, float* __restrict__ feat) {
    const int t    = threadIdx.x;
    const int lane = t & 63;
    const int wid  = t >> 6;
    const int wm   = wid >> 2;         // M half (32 rows)
    const int wn   = wid & 3;          // N quarter (32 cols)
    const int b    = blockIdx.x >> 3;
    const int l0   = (blockIdx.x & 7) << 6;

    const int mrow = lane & 15;
    const int koct = lane >> 4;

    f32x4 acc[2][2] = {};

    // A base: padded row (l0 + wm*32 + mrow) + kr, k-offset koct*8
    const ushort* xrow0 = xp + ((size_t)b * LPAD + (l0 + wm * 32 + mrow)) * EMBP + koct * 8;
    // B base: fragments nt = wn*2 + {0,1}
    const ushort* wlane = wf + (size_t)(wn * 2) * 512 + (size_t)lane * 8;

#pragma unroll
    for (int kr = 0; kr < 3; ++kr) {
        const ushort* xr = xrow0 + (size_t)kr * EMBP;
#pragma unroll
        for (int dc = 0; dc < 10; ++dc) {
            const int kc = kr * 10 + dc;
            bf16x8 a0 = *(const bf16x8*)(xr + dc * 32);
            bf16x8 a1 = *(const bf16x8*)(xr + 16 * EMBP + dc * 32);
            const ushort* wk = wlane + (size_t)kc * 4096;
            bf16x8 b0 = *(const bf16x8*)(wk);
            bf16x8 b1 = *(const bf16x8*)(wk + 512);
            acc[0][0] = __builtin_amdgcn_mfma_f32_16x16x32_bf16(a0, b0, acc[0][0], 0, 0, 0);
            acc[0][1] = __builtin_amdgcn_mfma_f32_16x16x32_bf16(a0, b1, acc[0][1], 0, 0, 0);
            acc[1][0] = __builtin_amdgcn_mfma_f32_16x16x32_bf16(a1, b0, acc[1][0], 0, 0, 0);
            acc[1][1] = __builtin_amdgcn_mfma_f32_16x16x32_bf16(a1, b1, acc[1][1], 0, 0, 0);
        }
    }

    // Epilogue: C/D layout col = lane&15, row = (lane>>4)*4 + r  [m91-verified]
#pragma unroll
    for (int n = 0; n < 2; ++n) {
        const int f = wn * 32 + n * 16 + mrow;
        const float bias = cb[f];
#pragma unroll
        for (int m = 0; m < 2; ++m) {
            const int lbase = l0 + wm * 32 + m * 16 + koct * 4;
#pragma unroll
            for (int r = 0; r < 4; ++r) {
                float v = acc[m][n][r] + bias;
                feat[((size_t)b * SEQL + (lbase + r)) * FMAPS + f] = relu_(v);
            }
        }
    }
}

// ---------------------------------------------------------------------------
// 3. ROI max-pool + collapsed FC. One wave per ROI; lane covers channels
//    {lane, lane+64}. 8 outputs via wave butterfly reductions.
// ---------------------------------------------------------------------------
__global__ __launch_bounds__(256) void roi_fc(
    const float* __restrict__ feat, const int* __restrict__ rois,
    const int* __restrict__ ridx, const float* __restrict__ mf,
    const float* __restrict__ b2, float* __restrict__ out) {
    const int w    = threadIdx.x >> 6;
    const int lane = threadIdx.x & 63;
    const int n    = blockIdx.x * 4 + w;       // grid 512 * 4 waves = 2048 exactly
    const int x1 = rois[n * 2 + 0];
    const int x2 = rois[n * 2 + 1];
    const int bi = ridx[n];
    const float* base = feat + ((size_t)bi * SEQL) * FMAPS;
    float m0 = -1e30f, m1 = -1e30f;
    for (int l = x1; l < x2; ++l) {
        const float* row = base + (size_t)l * FMAPS;
        m0 = fmaxf(m0, row[lane]);
        m1 = fmaxf(m1, row[lane + 64]);
    }
    float res[8];
#pragma unroll
    for (int c = 0; c < 8; ++c) {
        float p = m0 * mf[c * FMAPS + lane] + m1 * mf[c * FMAPS + 64 + lane];
#pragma unroll
        for (int off = 32; off; off >>= 1) p += __shfl_xor(p, off, 64);
        res[c] = p;
    }
    if (lane == 0) {
#pragma unroll
        for (int c = 0; c < 8; ++c) out[n * NCLS + c] = res[c] + b2[c];
    }
}

// ---------------------------------------------------------------------------
extern "C" void kernel_launch(void* const* d_in, const int* in_sizes, int n_in,
                              void* d_out, int out_size, void* d_ws, size_t ws_size,
                              hipStream_t stream) {
    const float* sentence = (const float*)d_in[0];
    const int*   rois     = (const int*)d_in[1];
    const int*   ridx     = (const int*)d_in[2];
    const float* conv_w   = (const float*)d_in[3];
    const float* conv_b   = (const float*)d_in[4];
    const float* fc1_w    = (const float*)d_in[5];
    const float* fc1_b    = (const float*)d_in[6];
    const float* cls_w    = (const float*)d_in[7];
    const float* cls_b    = (const float*)d_in[8];
    float* out = (float*)d_out;

    // workspace carve-up (bytes)
    char* ws = (char*)d_ws;
    ushort* Xp = (ushort*)ws;                                   // 64*514*320 bf16 = 21,053,440 B
    ushort* Wf = (ushort*)(ws + 21053440);                      // 122,880 bf16 = 245,760 B
    float*  Ft = (float*)(ws + 21053440 + 245760);              // 64*512*128 f32 = 16,777,216 B
    float*  Mf = (float*)(ws + 21053440 + 245760 + 16777216);   // 1024 f32
    float*  b2 = Mf + 1024;                                     // 8 f32

    hipLaunchKernelGGL(prep_fused,
                       dim3(PAD_BLOCKS + WPAD_BLOCKS + MF_BLOCKS + B2_BLOCKS), dim3(256), 0, stream,
                       sentence, conv_w, cls_w, fc1_w, fc1_b, cls_b, Xp, Wf, Mf, b2);
    hipLaunchKernelGGL(conv_mfma, dim3((BATCH * SEQL) / 64), dim3(512), 0, stream,
                       Xp, Wf, conv_b, Ft);
    hipLaunchKernelGGL(roi_fc, dim3(NROI / 4), dim3(256), 0, stream,
                       Ft, rois, ridx, Mf, b2, out);
}

// Round 5
// 132.228 us; speedup vs baseline: 1.1847x; 1.1847x over previous
//
#include <hip/hip_runtime.h>
#include <hip/hip_bf16.h>

// Problem constants
#define FMAPS 128     // feature maps
#define SEQL  512     // L
#define BATCH 64      // B
#define EMB   300     // embedding dim (fp32 sentence row = 1200 B, 16B-aligned)
#define NKC   30      // K-chunks of 32 (K = 3*320 = 960)
#define NROI  2048
#define FFDIM 512
#define NCLS  8

// prep grid carve-up (all blocks 256 threads): Mf partials FIRST (they're the
// longest pole), then b2, then Wf fragment build.
#define MF_BLOCKS   32     // 8 classes x 4 K-quarters -> deterministic partials
#define B2_BLOCKS   1
#define WPAD_BLOCKS 480    // 30*8*64*8 / 256

typedef short bf16x8 __attribute__((ext_vector_type(8)));   // 8 bf16 (4 VGPRs)
typedef float f32x4  __attribute__((ext_vector_type(4)));   // MFMA accumulator

static __device__ __forceinline__ float relu_(float x) { return x > 0.f ? x : 0.f; }
static __device__ __forceinline__ uint bf16bits(float f) {
    __hip_bfloat16 h = __float2bfloat16(f);
    return (uint)*reinterpret_cast<ushort*>(&h);
}

// ---------------------------------------------------------------------------
// 1. prep (heterogeneous grid, heavy blocks first):
//    [0,32)  : Mfp[q*8+c][g] = sum_{i in q-quarter} cls_w[c][i] * sum_p fc1_w[i][4g+p]
//    [32]    : b2[c] = cls_b[c] + cls_w[c]·fc1_b
//    [33,513): conv_w -> WF fragment-major bf16
//              WF[kc][nt][lane][j] = W[kc*32+(lane>>4)*8+j][nt*16+(lane&15)]
// ---------------------------------------------------------------------------
__global__ __launch_bounds__(256) void prep(
    const float* __restrict__ conv_w, const float* __restrict__ cls_w,
    const float* __restrict__ fc1_w, const float* __restrict__ fc1_b,
    const float* __restrict__ cls_b,
    ushort* __restrict__ wf, float* __restrict__ Mfp, float* __restrict__ b2) {
    __shared__ float red[2][128];
    const int tid = threadIdx.x;
    int blk = blockIdx.x;

    if (blk < MF_BLOCKS) {
        const int c = blk & 7, q = blk >> 3;
        const int g = tid & 127, ih = tid >> 7;
        const int i0 = q * 128 + ih * 64;
        float s = 0.f;
        for (int i = i0; i < i0 + 64; ++i) {
            float4 w4 = *(const float4*)(fc1_w + (size_t)i * FFDIM + 4 * g);
            s = fmaf(cls_w[c * FFDIM + i], (w4.x + w4.y) + (w4.z + w4.w), s);
        }
        red[ih][g] = s;
        __syncthreads();
        if (tid < 128) Mfp[(q * 8 + c) * FMAPS + tid] = red[0][tid] + red[1][tid];
        return;
    }
    blk -= MF_BLOCKS;

    if (blk < B2_BLOCKS) {
        const int c = tid >> 5, l32 = tid & 31;
        float s = 0.f;
        for (int i = l32; i < FFDIM; i += 32)
            s = fmaf(cls_w[c * FFDIM + i], fc1_b[i], s);
#pragma unroll
        for (int off = 16; off; off >>= 1) s += __shfl_xor(s, off, 64);
        if (l32 == 0) b2[c] = s + cls_b[c];
        return;
    }
    blk -= B2_BLOCKS;

    {   // Wf build
        int idx = blk * 256 + tid;                 // < 122,880 exactly
        int j    = idx & 7;
        int lane = (idx >> 3) & 63;
        int nt   = (idx >> 9) & 7;
        int kc   = idx >> 12;
        int f = nt * 16 + (lane & 15);
        int k = kc * 32 + (lane >> 4) * 8 + j;
        int kr = k / 320, d = k % 320;
        float v = (d < EMB) ? conv_w[f * 900 + kr * 300 + d] : 0.f;
        wf[idx] = (ushort)bf16bits(v);
    }
}

// ---------------------------------------------------------------------------
// 2. Conv as MFMA GEMM v3: LDS-staged A (whole K at once), direct-global B.
//    Block: 256 thr = 4 waves, tile 64(M) x 128(N); wave = 64x32 (Mr=4, Nr=2).
//    LDS: 66 rows x 320 bf16 (640 B/row) = 42240 B, XOR-swizzled:
//      16B-block i16 of row j stored at i16 ^ (j & 7)   [T2-style, bank-floor]
//    Staging reads the fp32 sentence directly (rows l0-1..l0+64, zero-padded)
//    and converts to bf16 in-register -> ds_write_b128.
// ---------------------------------------------------------------------------
__global__ __launch_bounds__(256) void conv_mfma(
    const float* __restrict__ sent, const ushort* __restrict__ wf,
    const float* __restrict__ cb, float* __restrict__ feat) {
    __shared__ __align__(16) ushort XL[66 * 320];   // 42240 B
    const int t    = threadIdx.x;
    const int lane = t & 63;
    const int wn   = t >> 6;            // N quarter: cols wn*32..+31
    const int b    = blockIdx.x >> 3;
    const int l0   = (blockIdx.x & 7) << 6;
    const int mrow = lane & 15;
    const int koct = lane >> 4;

    // ---- stage 2640 chunks (row j = c/40, 16B-block i16 = c%40) ----
#pragma unroll
    for (int it = 0; it < 11; ++it) {
        int c = it * 256 + t;
        if (c < 2640) {
            int j = c / 40, i16 = c - j * 40;
            int sr = l0 + j - 1;                       // sentence row (pad: -1, 512)
            int d0 = i16 * 8;                          // fp32 element offset
            float4 va = make_float4(0.f, 0.f, 0.f, 0.f), vb = va;
            if ((unsigned)sr < (unsigned)SEQL) {
                const float* srow = sent + ((size_t)b * SEQL + sr) * EMB;
                if (d0 < EMB)     va = *(const float4*)(srow + d0);      // d0<=296
                if (d0 + 4 < EMB) vb = *(const float4*)(srow + d0 + 4);  // d0<=292
            }
            uint4 pk;
            pk.x = bf16bits(va.x) | (bf16bits(va.y) << 16);
            pk.y = bf16bits(va.z) | (bf16bits(va.w) << 16);
            pk.z = bf16bits(vb.x) | (bf16bits(vb.y) << 16);
            pk.w = bf16bits(vb.z) | (bf16bits(vb.w) << 16);
            *(uint4*)((char*)XL + j * 640 + ((i16 ^ (j & 7)) << 4)) = pk;
        }
    }
    __syncthreads();

    // ---- compute ----
    f32x4 acc[4][2] = {};
    const ushort* wlane = wf + (size_t)(wn * 2) * 512 + (size_t)lane * 8;

#pragma unroll
    for (int kr = 0; kr < 3; ++kr) {
        const int sj = (mrow + kr) & 7;                // (j & 7) for all mr (mr*16≡0 mod 8)
#pragma unroll
        for (int dc = 0; dc < 10; ++dc) {
            const int kc = kr * 10 + dc;
            bf16x8 a[4];
#pragma unroll
            for (int mr = 0; mr < 4; ++mr) {
                const int j = mr * 16 + mrow + kr;
                a[mr] = *(const bf16x8*)((const char*)XL + j * 640 +
                                         (((dc * 4 + koct) ^ sj) << 4));
            }
            const ushort* wk = wlane + (size_t)kc * 4096;
            bf16x8 b0 = *(const bf16x8*)(wk);
            bf16x8 b1 = *(const bf16x8*)(wk + 512);
#pragma unroll
            for (int mr = 0; mr < 4; ++mr) {
                acc[mr][0] = __builtin_amdgcn_mfma_f32_16x16x32_bf16(a[mr], b0, acc[mr][0], 0, 0, 0);
                acc[mr][1] = __builtin_amdgcn_mfma_f32_16x16x32_bf16(a[mr], b1, acc[mr][1], 0, 0, 0);
            }
        }
    }

    // ---- epilogue: C/D layout col=lane&15, row=(lane>>4)*4+r [m91-verified] ----
#pragma unroll
    for (int nr = 0; nr < 2; ++nr) {
        const int f = wn * 32 + nr * 16 + mrow;
        const float bias = cb[f];
#pragma unroll
        for (int mr = 0; mr < 4; ++mr) {
            const int lb = l0 + mr * 16 + koct * 4;
#pragma unroll
            for (int r = 0; r < 4; ++r)
                feat[((size_t)b * SEQL + (lb + r)) * FMAPS + f] = relu_(acc[mr][nr][r] + bias);
        }
    }
}

// ---------------------------------------------------------------------------
// 3. ROI max-pool + collapsed FC, v2 (float4, 2 rows/iter).
//    Wave per ROI. lane = half(1b) | c4(5b): channels c4*4..+3, rows l0+half.
// ---------------------------------------------------------------------------
__global__ __launch_bounds__(256) void roi_fc(
    const float* __restrict__ feat, const int* __restrict__ rois,
    const int* __restrict__ ridx, const float* __restrict__ Mfp,
    const float* __restrict__ b2, float* __restrict__ out) {
    const int w    = threadIdx.x >> 6;
    const int lane = threadIdx.x & 63;
    const int n    = blockIdx.x * 4 + w;       // 512 blocks * 4 waves = 2048
    const int x1 = rois[n * 2 + 0];
    const int x2 = rois[n * 2 + 1];
    const int bi = ridx[n];
    const int half = lane >> 5, c4 = lane & 31;

    const float* base = feat + (size_t)bi * SEQL * FMAPS + c4 * 4;
    float4 m = make_float4(-1e30f, -1e30f, -1e30f, -1e30f);
    for (int l = x1 + half; l < x2; l += 2) {
        float4 v = *(const float4*)(base + (size_t)l * FMAPS);
        m.x = fmaxf(m.x, v.x); m.y = fmaxf(m.y, v.y);
        m.z = fmaxf(m.z, v.z); m.w = fmaxf(m.w, v.w);
    }
    // merge the two half-wave row groups
    m.x = fmaxf(m.x, __shfl_xor(m.x, 32, 64));
    m.y = fmaxf(m.y, __shfl_xor(m.y, 32, 64));
    m.z = fmaxf(m.z, __shfl_xor(m.z, 32, 64));
    m.w = fmaxf(m.w, __shfl_xor(m.w, 32, 64));

    const float4* M4 = (const float4*)Mfp;     // [(q*8+c)*32 + c4]
#pragma unroll
    for (int c = 0; c < 8; ++c) {
        float4 w0 = M4[(c) * 32 + c4];
        float4 w1 = M4[(8 + c) * 32 + c4];
        float4 w2 = M4[(16 + c) * 32 + c4];
        float4 w3 = M4[(24 + c) * 32 + c4];
        float4 wv;
        wv.x = (w0.x + w1.x) + (w2.x + w3.x);
        wv.y = (w0.y + w1.y) + (w2.y + w3.y);
        wv.z = (w0.z + w1.z) + (w2.z + w3.z);
        wv.w = (w0.w + w1.w) + (w2.w + w3.w);
        float p = m.x * wv.x + m.y * wv.y + m.z * wv.z + m.w * wv.w;
#pragma unroll
        for (int off = 16; off; off >>= 1) p += __shfl_xor(p, off, 64);
        if (lane == 0) out[n * NCLS + c] = p + b2[c];
    }
}

// ---------------------------------------------------------------------------
extern "C" void kernel_launch(void* const* d_in, const int* in_sizes, int n_in,
                              void* d_out, int out_size, void* d_ws, size_t ws_size,
                              hipStream_t stream) {
    const float* sentence = (const float*)d_in[0];
    const int*   rois     = (const int*)d_in[1];
    const int*   ridx     = (const int*)d_in[2];
    const float* conv_w   = (const float*)d_in[3];
    const float* conv_b   = (const float*)d_in[4];
    const float* fc1_w    = (const float*)d_in[5];
    const float* fc1_b    = (const float*)d_in[6];
    const float* cls_w    = (const float*)d_in[7];
    const float* cls_b    = (const float*)d_in[8];
    float* out = (float*)d_out;

    // workspace carve-up (bytes)
    char* ws = (char*)d_ws;
    float*  Ft  = (float*)ws;                          // 64*512*128 f32 = 16,777,216 B
    ushort* Wf  = (ushort*)(ws + 16777216);            // 122,880 bf16  = 245,760 B
    float*  Mfp = (float*)(ws + 16777216 + 245760);    // 32*128 f32    = 16,384 B
    float*  b2  = Mfp + 4096;                          // 8 f32

    hipLaunchKernelGGL(prep, dim3(MF_BLOCKS + B2_BLOCKS + WPAD_BLOCKS), dim3(256), 0, stream,
                       conv_w, cls_w, fc1_w, fc1_b, cls_b, Wf, Mfp, b2);
    hipLaunchKernelGGL(conv_mfma, dim3((BATCH * SEQL) / 64), dim3(256), 0, stream,
                       sentence, Wf, conv_b, Ft);
    hipLaunchKernelGGL(roi_fc, dim3(NROI / 4), dim3(256), 0, stream,
                       Ft, rois, ridx, Mfp, b2, out);
}